// Round 8
// baseline (879.249 us; speedup 1.0000x reference)
//
#include <hip/hip_runtime.h>

#define N_NODES 50000
#define N_EDGES 800000
#define D_IN    64
#define D_HID   128
#define NBLK    ((N_NODES + 255) / 256)   // 196
#define NODEB   (N_NODES / 4)             // 12500 node-blocks (4 waves/block)

__device__ __forceinline__ float bf2f(unsigned short u) {
    return __uint_as_float(((unsigned)u) << 16);
}
__device__ __forceinline__ unsigned short f2bf(float f) {
    unsigned u = __float_as_uint(f);
    return (unsigned short)((u + 0x7FFFu + ((u >> 16) & 1u)) >> 16);
}

// ---- CSR build ----
__global__ void k_count(const int* __restrict__ rcv, int* __restrict__ deg) {
    int i = blockIdx.x * blockDim.x + threadIdx.x;
    if (i < N_EDGES) atomicAdd(&deg[rcv[i]], 1);
}

__global__ void k_blocksum(const int* __restrict__ deg, int* __restrict__ bsum) {
    int b = blockIdx.x, t = threadIdx.x;
    int i = b * 256 + t;
    int v = (i < N_NODES) ? deg[i] : 0;
#pragma unroll
    for (int o = 32; o >= 1; o >>= 1) v += __shfl_down(v, o);
    __shared__ int s[4];
    if ((t & 63) == 0) s[t >> 6] = v;
    __syncthreads();
    if (t == 0) bsum[b] = s[0] + s[1] + s[2] + s[3];
}

__global__ void k_scanb(const int* __restrict__ bsum, int* __restrict__ boff) {
    __shared__ int sh[256];
    int t = threadIdx.x;
    int v = (t < NBLK) ? bsum[t] : 0;
    sh[t] = v;
    __syncthreads();
    for (int d = 1; d < 256; d <<= 1) {
        int u = (t >= d) ? sh[t - d] : 0;
        __syncthreads();
        sh[t] += u;
        __syncthreads();
    }
    boff[t] = sh[t] - v;   // exclusive
}

__global__ void k_offsets(const int* __restrict__ deg, const int* __restrict__ boff,
                          int* __restrict__ off, int* __restrict__ cursor,
                          float* __restrict__ inv) {
    __shared__ int sh[256];
    int b = blockIdx.x, t = threadIdx.x, i = b * 256 + t;
    int d = (i < N_NODES) ? deg[i] : 0;
    sh[t] = d;
    __syncthreads();
    for (int o = 1; o < 256; o <<= 1) {
        int u = (t >= o) ? sh[t - o] : 0;
        __syncthreads();
        sh[t] += u;
        __syncthreads();
    }
    if (i < N_NODES) {
        int excl = boff[b] + sh[t] - d;
        off[i] = excl;
        cursor[i] = excl;
        inv[i] = d > 0 ? 1.0f / (float)d : 0.0f;
    }
    if (b == 0 && t == 0) off[N_NODES] = N_EDGES;
}

// packed (sender, weight-bits) CSR fill
__global__ void k_fill(const int* __restrict__ snd, const int* __restrict__ rcv,
                       const float* __restrict__ w,
                       int* __restrict__ cursor, int2* __restrict__ e_sw) {
    int i = blockIdx.x * blockDim.x + threadIdx.x;
    if (i >= N_EDGES) return;
    int r = rcv[i];
    int p = atomicAdd(&cursor[r], 1);
    e_sw[p] = make_int2(snd[i], __float_as_int(w[i]));
}

// ---- fp32 -> bf16 pair-packed conversion (initial h0 only) ----
__global__ void k_tobf(const float* __restrict__ src, unsigned int* __restrict__ dst,
                       int npairs) {
    int i = blockIdx.x * blockDim.x + threadIdx.x;
    if (i >= npairs) return;
    float2 v = *(const float2*)(src + (size_t)i * 2);
    dst[i] = (unsigned)f2bf(v.x) | ((unsigned)f2bf(v.y) << 16);
}

// ---- feature-sliced gather + residual update ----
// Slice = blockIdx.x % NS (16 feats wide) -> with round-robin block->XCD
// dispatch, each XCD's L2 only sees its 1.6 MB slice of hb (L2-resident).
// One wave per (node, slice); lane = sub*16 + feat: 4 edges in parallel,
// combined via shfl_xor(16/32). Writes pre = h*se + pool*inv (fp32).
template<int DIN, int NS>
__global__ __launch_bounds__(256) void k_gather(
        const float* __restrict__ h,            // fp32 h_i (residual rows)
        const unsigned short* __restrict__ hb,  // bf16 h_i (neighbor rows)
        const int* __restrict__ off,
        const int2* __restrict__ e_sw,
        const float* __restrict__ inv,
        const float* __restrict__ eps, int li,
        float* __restrict__ pre) {
    int bid = blockIdx.x;
    int s   = bid % NS;
    int nb  = bid / NS;
    int wave = threadIdx.x >> 6;
    int lane = threadIdx.x & 63;
    int n = nb * 4 + wave;                      // NODEB*4 == N_NODES exactly
    int sub = lane >> 4;
    int f   = s * 16 + (lane & 15);

    int e0 = off[n], e1 = off[n + 1];
    float pool = 0.0f;
    for (int e = e0; e < e1; e += 4) {
        int ee = e + sub;
        int2 sw = e_sw[ee < e1 ? ee : e1 - 1];
        float w = (ee < e1) ? __int_as_float(sw.y) : 0.0f;
        pool += bf2f(hb[(size_t)sw.x * DIN + f]) * w;
    }
    pool += __shfl_xor(pool, 16);
    pool += __shfl_xor(pool, 32);

    if (lane < 16) {
        float se = 1.0f + eps[li];
        se = se > 0.0f ? se : 0.0f;             // relu(1+eps)
        float pr = h[(size_t)n * DIN + f] * se + pool * inv[n];
        pre[(size_t)n * DIN + f] = pr;
    }
}

// ---- per-row MLP; optionally fuses bf16 conversion of the output ----
template<int DIN, int DOUT, bool RELU, bool WBF>
__global__ __launch_bounds__(256) void k_mlp(const float* __restrict__ pre,
                                             const float* __restrict__ W,
                                             const float* __restrict__ b,
                                             float* __restrict__ out,
                                             unsigned short* __restrict__ hbout) {
    int wave = threadIdx.x >> 6;
    int lane = threadIdx.x & 63;
    int n = blockIdx.x * 4 + wave;
    if (n >= N_NODES) return;

    const float* hr = pre + (size_t)n * DIN;
    float p[DIN / 64];
#pragma unroll
    for (int k = 0; k < DIN / 64; ++k) p[k] = hr[lane + 64 * k];

    float acc[DOUT / 64];
#pragma unroll
    for (int k = 0; k < DOUT / 64; ++k) acc[k] = b[lane + 64 * k];
#pragma unroll
    for (int d = 0; d < DIN; ++d) {
        float pd = __shfl(p[d >> 6], d & 63);
#pragma unroll
        for (int k = 0; k < DOUT / 64; ++k)
            acc[k] += pd * W[d * DOUT + lane + 64 * k];
    }
    float* orow = out + (size_t)n * DOUT;
#pragma unroll
    for (int k = 0; k < DOUT / 64; ++k) {
        float v = acc[k];
        if (RELU) v = v > 0.0f ? v : 0.0f;
        orow[lane + 64 * k] = v;
        if (WBF) hbout[(size_t)n * DOUT + lane + 64 * k] = f2bf(v);
    }
}

extern "C" void kernel_launch(void* const* d_in, const int* in_sizes, int n_in,
                              void* d_out, int out_size, void* d_ws, size_t ws_size,
                              hipStream_t stream) {
    const float* h0  = (const float*)d_in[0];
    const float* wts = (const float*)d_in[1];
    const int*   snd = (const int*)d_in[2];
    const int*   rcv = (const int*)d_in[3];
    const float* W0  = (const float*)d_in[4];
    const float* b0  = (const float*)d_in[5];
    const float* W1  = (const float*)d_in[6];
    const float* b1  = (const float*)d_in[7];
    const float* W2  = (const float*)d_in[8];
    const float* b2  = (const float*)d_in[9];
    const float* eps = (const float*)d_in[10];

    float* out0 = (float*)d_out;                  // final: node_embeddings
    float* out1 = out0 + (size_t)N_NODES * D_HID; // final: h

    // ws (~20 MB): deg|bsum|boff|off|cursor|inv | e_sw(int2) | hb(bf16)
    int*   deg    = (int*)d_ws;
    int*   bsum   = deg + N_NODES;
    int*   boff   = bsum + 256;
    int*   off    = boff + 256;
    int*   cursor = off + N_NODES + 2;            // keeps e_sw 8B-aligned
    float* inv    = (float*)(cursor + N_NODES);
    int2*  e_sw   = (int2*)(inv + N_NODES);
    unsigned int*   hb32 = (unsigned int*)(e_sw + N_EDGES);
    unsigned short* hb   = (unsigned short*)hb32;

    hipMemsetAsync(deg, 0, (size_t)N_NODES * sizeof(int), stream);
    k_count<<<(N_EDGES + 255) / 256, 256, 0, stream>>>(rcv, deg);
    k_blocksum<<<NBLK, 256, 0, stream>>>(deg, bsum);
    k_scanb<<<1, 256, 0, stream>>>(bsum, boff);
    k_offsets<<<NBLK, 256, 0, stream>>>(deg, boff, off, cursor, inv);
    k_fill<<<(N_EDGES + 255) / 256, 256, 0, stream>>>(snd, rcv, wts, cursor, e_sw);

    // initial bf16 copy of h0
    k_tobf<<<(N_NODES * D_IN / 2 + 255) / 256, 256, 0, stream>>>(
        h0, hb32, N_NODES * D_IN / 2);

    // L0: gather(h0) -> pre0 in out0 ; mlp0: out0 -> out1 (+hb of h1)
    k_gather<D_IN, 4><<<NODEB * 4, 256, 0, stream>>>(
        h0, hb, off, e_sw, inv, eps, 0, out0);
    k_mlp<D_IN, D_HID, true, true><<<NODEB, 256, 0, stream>>>(
        out0, W0, b0, out1, hb);

    // L1: gather(h1=out1) -> pre1 in out0 ; mlp1: out0 -> out1 (+hb of h2)
    k_gather<D_HID, 8><<<NODEB * 8, 256, 0, stream>>>(
        out1, hb, off, e_sw, inv, eps, 1, out0);
    k_mlp<D_HID, D_HID, true, true><<<NODEB, 256, 0, stream>>>(
        out0, W1, b1, out1, hb);

    // L2a: gather(h2=out1) -> pre2 = node_embeddings (out0)
    k_gather<D_HID, 8><<<NODEB * 8, 256, 0, stream>>>(
        out1, hb, off, e_sw, inv, eps, 2, out0);
    // L2b: final MLP (no relu): out0 -> out1
    k_mlp<D_HID, D_HID, false, false><<<NODEB, 256, 0, stream>>>(
        out0, W2, b2, out1, nullptr);
}

// Round 10
// 633.516 us; speedup vs baseline: 1.3879x; 1.3879x over previous
//
#include <hip/hip_runtime.h>

#define N_NODES 50000
#define N_EDGES 800000
#define D_IN    64
#define D_HID   128
#define NBLK    ((N_NODES + 255) / 256)   // 196
#define NODEB   (N_NODES / 4)             // 12500 blocks x 4 waves

__device__ __forceinline__ float blo(unsigned r) { return __uint_as_float(r << 16); }
__device__ __forceinline__ float bhi(unsigned r) { return __uint_as_float(r & 0xFFFF0000u); }
__device__ __forceinline__ unsigned short f2bf(float f) {
    unsigned u = __float_as_uint(f);
    return (unsigned short)((u + 0x7FFFu + ((u >> 16) & 1u)) >> 16);
}

// ---- CSR build ----
__global__ void k_count(const int* __restrict__ rcv, int* __restrict__ deg) {
    int i = blockIdx.x * blockDim.x + threadIdx.x;
    if (i < N_EDGES) atomicAdd(&deg[rcv[i]], 1);
}

__global__ void k_blocksum(const int* __restrict__ deg, int* __restrict__ bsum) {
    int b = blockIdx.x, t = threadIdx.x;
    int i = b * 256 + t;
    int v = (i < N_NODES) ? deg[i] : 0;
#pragma unroll
    for (int o = 32; o >= 1; o >>= 1) v += __shfl_down(v, o);
    __shared__ int s[4];
    if ((t & 63) == 0) s[t >> 6] = v;
    __syncthreads();
    if (t == 0) bsum[b] = s[0] + s[1] + s[2] + s[3];
}

__global__ void k_scanb(const int* __restrict__ bsum, int* __restrict__ boff) {
    __shared__ int sh[256];
    int t = threadIdx.x;
    int v = (t < NBLK) ? bsum[t] : 0;
    sh[t] = v;
    __syncthreads();
    for (int d = 1; d < 256; d <<= 1) {
        int u = (t >= d) ? sh[t - d] : 0;
        __syncthreads();
        sh[t] += u;
        __syncthreads();
    }
    boff[t] = sh[t] - v;   // exclusive
}

__global__ void k_offsets(const int* __restrict__ deg, const int* __restrict__ boff,
                          int* __restrict__ off, int* __restrict__ cursor,
                          float* __restrict__ inv) {
    __shared__ int sh[256];
    int b = blockIdx.x, t = threadIdx.x, i = b * 256 + t;
    int d = (i < N_NODES) ? deg[i] : 0;
    sh[t] = d;
    __syncthreads();
    for (int o = 1; o < 256; o <<= 1) {
        int u = (t >= o) ? sh[t - o] : 0;
        __syncthreads();
        sh[t] += u;
        __syncthreads();
    }
    if (i < N_NODES) {
        int excl = boff[b] + sh[t] - d;
        off[i] = excl;
        cursor[i] = excl;
        inv[i] = d > 0 ? 1.0f / (float)d : 0.0f;
    }
    if (b == 0 && t == 0) off[N_NODES] = N_EDGES;
}

__global__ void k_fill(const int* __restrict__ snd, const int* __restrict__ rcv,
                       const float* __restrict__ w,
                       int* __restrict__ cursor, int2* __restrict__ e_sw) {
    int i = blockIdx.x * blockDim.x + threadIdx.x;
    if (i >= N_EDGES) return;
    int r = rcv[i];
    int p = atomicAdd(&cursor[r], 1);
    e_sw[p] = make_int2(snd[i], __float_as_int(w[i]));
}

// ---- fp32 -> bf16 pair-packed ----
__global__ void k_tobf(const float* __restrict__ src, unsigned int* __restrict__ dst,
                       int npairs) {
    int i = blockIdx.x * blockDim.x + threadIdx.x;
    if (i >= npairs) return;
    float2 v = *(const float2*)(src + (size_t)i * 2);
    dst[i] = (unsigned)f2bf(v.x) | ((unsigned)f2bf(v.y) << 16);
}

// ---- fused layer: gather (bf16 rows, 1 dword/lane/row) + residual (+ MLP) ----
// One wave per node. Lane l holds feats {2l,2l+1} (D=128) or {2(l&31),...} with
// half-wave edge-split (D=64). Edge descriptors loaded once per 64 edges as a
// lane-distributed int2 (single coalesced load), broadcast per edge via shfl;
// inner loop = row-load (4 independent in flight) + 2 fma.
// NOTE: hbw is READ-ONLY here (bf16 refresh happens in a separate k_tobf pass
// between layers — fusing it raced in round 9).
template<int DIN, bool RELU, bool DO_MLP>
__global__ __launch_bounds__(256) void k_layer(
        const float* __restrict__ h,             // fp32 rows (residual; may alias out)
        const unsigned* __restrict__ hbw,        // bf16 rows, pair-packed uints
        const int* __restrict__ off,
        const int2* __restrict__ e_sw,
        const float* __restrict__ inv,
        const float* __restrict__ eps, int li,
        const float* __restrict__ W,
        const float* __restrict__ b,
        float* __restrict__ out) {
    constexpr int RW = DIN / 2;                  // uints per row
    int wave = threadIdx.x >> 6;
    int lane = threadIdx.x & 63;
    int n = blockIdx.x * 4 + wave;               // NODEB*4 == N_NODES

    int e0 = off[n], e1 = off[n + 1];
    float px = 0.0f, py = 0.0f;

    int e = e0;
    while (e < e1) {
        int idx = e + lane;
        int2 dl = e_sw[idx < e1 ? idx : e1 - 1]; // 64 descs, one coalesced load
        int cnt = (e1 - e) < 64 ? (e1 - e) : 64;
        int j = 0;
        if constexpr (DIN == 128) {
            const int f = lane;
            for (; j + 4 <= cnt; j += 4) {
                int   s0 = __shfl(dl.x, j),     s1 = __shfl(dl.x, j + 1);
                int   s2 = __shfl(dl.x, j + 2), s3 = __shfl(dl.x, j + 3);
                float w0 = __int_as_float(__shfl(dl.y, j));
                float w1 = __int_as_float(__shfl(dl.y, j + 1));
                float w2 = __int_as_float(__shfl(dl.y, j + 2));
                float w3 = __int_as_float(__shfl(dl.y, j + 3));
                unsigned r0 = hbw[(size_t)s0 * RW + f];
                unsigned r1 = hbw[(size_t)s1 * RW + f];
                unsigned r2 = hbw[(size_t)s2 * RW + f];
                unsigned r3 = hbw[(size_t)s3 * RW + f];
                px += blo(r0) * w0 + blo(r1) * w1 + blo(r2) * w2 + blo(r3) * w3;
                py += bhi(r0) * w0 + bhi(r1) * w1 + bhi(r2) * w2 + bhi(r3) * w3;
            }
            for (; j < cnt; ++j) {
                int   s0 = __shfl(dl.x, j);
                float w0 = __int_as_float(__shfl(dl.y, j));
                unsigned r0 = hbw[(size_t)s0 * RW + f];
                px += blo(r0) * w0;
                py += bhi(r0) * w0;
            }
        } else {                                 // DIN==64: half-wave per edge
            const int sub = lane >> 5;
            const int m   = lane & 31;
            for (; j + 8 <= cnt; j += 8) {
                int   s0 = __shfl(dl.x, j + sub),     s1 = __shfl(dl.x, j + 2 + sub);
                int   s2 = __shfl(dl.x, j + 4 + sub), s3 = __shfl(dl.x, j + 6 + sub);
                float w0 = __int_as_float(__shfl(dl.y, j + sub));
                float w1 = __int_as_float(__shfl(dl.y, j + 2 + sub));
                float w2 = __int_as_float(__shfl(dl.y, j + 4 + sub));
                float w3 = __int_as_float(__shfl(dl.y, j + 6 + sub));
                unsigned r0 = hbw[(size_t)s0 * RW + m];
                unsigned r1 = hbw[(size_t)s1 * RW + m];
                unsigned r2 = hbw[(size_t)s2 * RW + m];
                unsigned r3 = hbw[(size_t)s3 * RW + m];
                px += blo(r0) * w0 + blo(r1) * w1 + blo(r2) * w2 + blo(r3) * w3;
                py += bhi(r0) * w0 + bhi(r1) * w1 + bhi(r2) * w2 + bhi(r3) * w3;
            }
            for (; j < cnt; j += 2) {
                int ee = j + sub;
                bool valid = ee < cnt;
                int   s0 = __shfl(dl.x, valid ? ee : j);
                float w0 = valid ? __int_as_float(__shfl(dl.y, ee)) : 0.0f;
                unsigned r0 = hbw[(size_t)s0 * RW + m];
                px += blo(r0) * w0;
                py += bhi(r0) * w0;
            }
        }
        e += cnt;
    }
    if constexpr (DIN == 64) {
        px += __shfl_xor(px, 32);
        py += __shfl_xor(py, 32);
    }

    float se = 1.0f + eps[li];
    se = se > 0.0f ? se : 0.0f;                  // relu(1+eps)
    float id = inv[n];

    const int m = (DIN == 128) ? lane : (lane & 31);
    float2 hv = ((const float2*)(h + (size_t)n * DIN))[m];
    float prex = hv.x * se + px * id;
    float prey = hv.y * se + py * id;

    if constexpr (!DO_MLP) {
        // safe even when out == h: neighbor data came from hbw, and row n is
        // read (hv) before written, both by this wave only.
        ((float2*)(out + (size_t)n * DIN))[m] = make_float2(prex, prey);
        return;
    }

    // MLP: DIN -> 128, acc cols {2l, 2l+1}
    float2 acc = ((const float2*)b)[lane];
#pragma unroll
    for (int d = 0; d < DIN; ++d) {
        float pd = __shfl((d & 1) ? prey : prex, d >> 1);
        float2 wv = ((const float2*)(W + (size_t)d * 128))[lane];
        acc.x += pd * wv.x;
        acc.y += pd * wv.y;
    }
    if (RELU) {
        acc.x = acc.x > 0.0f ? acc.x : 0.0f;
        acc.y = acc.y > 0.0f ? acc.y : 0.0f;
    }
    ((float2*)(out + (size_t)n * 128))[lane] = acc;
}

// ---- final standalone MLP (layer-2 tail; float2 {2l,2l+1} layout) ----
__global__ __launch_bounds__(256) void k_mlp(const float* __restrict__ pre,
                                             const float* __restrict__ W,
                                             const float* __restrict__ b,
                                             float* __restrict__ out) {
    int wave = threadIdx.x >> 6;
    int lane = threadIdx.x & 63;
    int n = blockIdx.x * 4 + wave;

    float2 p = ((const float2*)(pre + (size_t)n * 128))[lane];
    float2 acc = ((const float2*)b)[lane];
#pragma unroll
    for (int d = 0; d < 128; ++d) {
        float pd = __shfl((d & 1) ? p.y : p.x, d >> 1);
        float2 wv = ((const float2*)(W + (size_t)d * 128))[lane];
        acc.x += pd * wv.x;
        acc.y += pd * wv.y;
    }
    ((float2*)(out + (size_t)n * 128))[lane] = acc;
}

extern "C" void kernel_launch(void* const* d_in, const int* in_sizes, int n_in,
                              void* d_out, int out_size, void* d_ws, size_t ws_size,
                              hipStream_t stream) {
    const float* h0  = (const float*)d_in[0];
    const float* wts = (const float*)d_in[1];
    const int*   snd = (const int*)d_in[2];
    const int*   rcv = (const int*)d_in[3];
    const float* W0  = (const float*)d_in[4];
    const float* b0  = (const float*)d_in[5];
    const float* W1  = (const float*)d_in[6];
    const float* b1  = (const float*)d_in[7];
    const float* W2  = (const float*)d_in[8];
    const float* b2  = (const float*)d_in[9];
    const float* eps = (const float*)d_in[10];

    float* out0 = (float*)d_out;                  // final: node_embeddings
    float* out1 = out0 + (size_t)N_NODES * D_HID; // final: h

    // ws (~20.5 MB): deg|bsum|boff|off|cursor|inv | e_sw(int2) | hbw(bf16 pairs)
    int*   deg    = (int*)d_ws;
    int*   bsum   = deg + N_NODES;
    int*   boff   = bsum + 256;
    int*   off    = boff + 256;
    int*   cursor = off + N_NODES + 2;            // keeps e_sw 8B-aligned
    float* inv    = (float*)(cursor + N_NODES);
    int2*  e_sw   = (int2*)(inv + N_NODES);
    unsigned* hbw = (unsigned*)(e_sw + N_EDGES);  // up to 50000*64 uints = 12.8MB

    hipMemsetAsync(deg, 0, (size_t)N_NODES * sizeof(int), stream);
    k_count<<<(N_EDGES + 255) / 256, 256, 0, stream>>>(rcv, deg);
    k_blocksum<<<NBLK, 256, 0, stream>>>(deg, bsum);
    k_scanb<<<1, 256, 0, stream>>>(bsum, boff);
    k_offsets<<<NBLK, 256, 0, stream>>>(deg, boff, off, cursor, inv);
    k_fill<<<(N_EDGES + 255) / 256, 256, 0, stream>>>(snd, rcv, wts, cursor, e_sw);

    // L0: tobf(h0) ; gather(h0)+mlp0 -> out0 (= h1)
    k_tobf<<<(N_NODES * D_IN / 2 + 255) / 256, 256, 0, stream>>>(
        h0, hbw, N_NODES * D_IN / 2);
    k_layer<D_IN, true, true><<<NODEB, 256, 0, stream>>>(
        h0, hbw, off, e_sw, inv, eps, 0, W0, b0, out0);

    // L1: tobf(h1) ; gather(h1)+mlp1 -> out1 (= h2)
    k_tobf<<<(N_NODES * D_HID / 2 + 255) / 256, 256, 0, stream>>>(
        out0, hbw, N_NODES * D_HID / 2);
    k_layer<D_HID, true, true><<<NODEB, 256, 0, stream>>>(
        out0, hbw, off, e_sw, inv, eps, 1, W1, b1, out1);

    // L2a: tobf(h2) ; gather(h2) -> out0 (= node_embeddings)
    k_tobf<<<(N_NODES * D_HID / 2 + 255) / 256, 256, 0, stream>>>(
        out1, hbw, N_NODES * D_HID / 2);
    k_layer<D_HID, false, false><<<NODEB, 256, 0, stream>>>(
        out1, hbw, off, e_sw, inv, eps, 2, nullptr, nullptr, out0);

    // L2b: final MLP (no relu): out0 -> out1
    k_mlp<<<NODEB, 256, 0, stream>>>(out0, W2, b2, out1);
}